// Round 5
// baseline (405.823 us; speedup 1.0000x reference)
//
#include <hip/hip_runtime.h>

typedef __bf16 bf16x8 __attribute__((ext_vector_type(8)));
typedef float f32x4 __attribute__((ext_vector_type(4)));

#define DIM 1024
#define NSEQ 2048

// ---------------- RMSNorm: fp32 in, bf16 out ----------------
__global__ __launch_bounds__(256) void rmsnorm_kernel(const float* __restrict__ x,
                                                      const float* __restrict__ g,
                                                      __bf16* __restrict__ o) {
    int row = blockIdx.x;
    int t = threadIdx.x;
    float4 xv = ((const float4*)(x + (size_t)row * DIM))[t];
    float ss = xv.x*xv.x + xv.y*xv.y + xv.z*xv.z + xv.w*xv.w;
    #pragma unroll
    for (int off = 32; off; off >>= 1) ss += __shfl_xor(ss, off, 64);
    __shared__ float red[4];
    if ((t & 63) == 0) red[t >> 6] = ss;
    __syncthreads();
    ss = red[0] + red[1] + red[2] + red[3];
    float r = rsqrtf(ss * (1.0f / 1024.0f) + 1.1920929e-07f);
    float4 gv = ((const float4*)g)[t];
    union { uint2 u; __bf16 h[4]; } p;
    p.h[0] = (__bf16)(xv.x * r * gv.x);
    p.h[1] = (__bf16)(xv.y * r * gv.y);
    p.h[2] = (__bf16)(xv.z * r * gv.z);
    p.h[3] = (__bf16)(xv.w * r * gv.w);
    *(uint2*)(o + (size_t)row * DIM + t * 4) = p.u;
}

// ---------------- RoPE in-place on (4096 x 1024) bf16, heads of 64 ----------------
__global__ __launch_bounds__(256) void rope_kernel(__bf16* __restrict__ x) {
    int gid = blockIdx.x * 256 + threadIdx.x;   // one pair per thread
    int row = gid >> 9;          // 512 pairs per row
    int pr = gid & 511;
    int pos = row & (NSEQ - 1);
    int dp = pr & 31;            // pair index within head
    float inv = __expf(-(float)dp * (9.210340371976184f / 32.0f)); // 10000^(-2dp/64)
    float ang = (float)pos * inv;
    float sn, cs;
    sincosf(ang, &sn, &cs);
    size_t off = (size_t)row * DIM + pr * 2;
    union { unsigned int u; __bf16 h[2]; } p;
    p.u = *(const unsigned int*)(x + off);
    float x1 = (float)p.h[0], x2 = (float)p.h[1];
    p.h[0] = (__bf16)(x1 * cs - x2 * sn);
    p.h[1] = (__bf16)(x2 * cs + x1 * sn);
    *(unsigned int*)(x + off) = p.u;
}

// ---------------- GEMM: C[i,j] = scale * sum_k A[i,k] * B[j,k] ----------------
// A: M x 1024 (bf16 or fp32), B: N x 1024 (bf16 or fp32; fp32 converted to bf16
// during LDS staging), C: M x N with row stride ldc (bf16 or fp32).
// Double-buffered LDS + register prefetch: one barrier per K-tile.
#define LDT 40   // padded LDS stride (elements); 2-way-free banks

template <typename T>
__device__ __forceinline__ void load_tile_regs(const T* __restrict__ P, int base_row,
                                               int k0, int t, uint4* r) {
    if constexpr (sizeof(T) == 2) {
        #pragma unroll
        for (int it = 0; it < 2; ++it) {
            int idx = t + it * 256;          // 512 x 16B covers 128x32 bf16
            int row = idx >> 2;
            int c8 = (idx & 3) * 8;
            r[it] = *(const uint4*)((const __bf16*)P + (size_t)(base_row + row) * 1024 + k0 + c8);
        }
    } else {
        #pragma unroll
        for (int it = 0; it < 4; ++it) {
            int idx = t + it * 256;          // 1024 x 16B covers 128x32 fp32
            int row = idx >> 3;
            int c4 = (idx & 7) * 4;
            r[it] = *(const uint4*)((const float*)P + (size_t)(base_row + row) * 1024 + k0 + c4);
        }
    }
}

template <typename T>
__device__ __forceinline__ void store_tile_lds(__bf16* S, int t, const uint4* r) {
    if constexpr (sizeof(T) == 2) {
        #pragma unroll
        for (int it = 0; it < 2; ++it) {
            int idx = t + it * 256;
            int row = idx >> 2;
            int c8 = (idx & 3) * 8;
            *(uint4*)&S[row * LDT + c8] = r[it];
        }
    } else {
        #pragma unroll
        for (int it = 0; it < 4; ++it) {
            int idx = t + it * 256;
            int row = idx >> 3;
            int c4 = (idx & 7) * 4;
            union { uint4 q; float f[4]; } u; u.q = r[it];
            union { uint2 u2; __bf16 h[4]; } pk;
            pk.h[0] = (__bf16)u.f[0]; pk.h[1] = (__bf16)u.f[1];
            pk.h[2] = (__bf16)u.f[2]; pk.h[3] = (__bf16)u.f[3];
            *(uint2*)&S[row * LDT + c4] = pk.u2;
        }
    }
}

template <typename AT, typename BT, typename CT>
__global__ __launch_bounds__(256) void gemm_bt_kernel(const AT* __restrict__ A,
                                                      const BT* __restrict__ B,
                                                      CT* __restrict__ C,
                                                      float scale, int ldc) {
    __shared__ __bf16 As[2][128 * LDT];
    __shared__ __bf16 Bs[2][128 * LDT];
    int bm = blockIdx.x, bn = blockIdx.y;
    int t = threadIdx.x;
    int w = t >> 6, l = t & 63;
    int wm = (w >> 1) * 64, wn = (w & 1) * 64;   // wave 2x2 grid, each 64x64
    int lrow = l & 15, lq = l >> 4;
    f32x4 acc[4][4] = {};
    uint4 ra[sizeof(AT)], rb[sizeof(BT)];        // 2 (bf16) or 4 (fp32) regs used

    load_tile_regs<AT>(A, bm * 128, 0, t, ra);
    load_tile_regs<BT>(B, bn * 128, 0, t, rb);
    store_tile_lds<AT>(As[0], t, ra);
    store_tile_lds<BT>(Bs[0], t, rb);
    __syncthreads();

    for (int kt = 0; kt < 32; ++kt) {
        int cur = kt & 1;
        if (kt < 31) {
            load_tile_regs<AT>(A, bm * 128, (kt + 1) * 32, t, ra);
            load_tile_regs<BT>(B, bn * 128, (kt + 1) * 32, t, rb);
        }
        bf16x8 af[4], bfr[4];
        #pragma unroll
        for (int i = 0; i < 4; ++i)
            af[i] = *(const bf16x8*)&As[cur][(wm + i * 16 + lrow) * LDT + lq * 8];
        #pragma unroll
        for (int i = 0; i < 4; ++i)
            bfr[i] = *(const bf16x8*)&Bs[cur][(wn + i * 16 + lrow) * LDT + lq * 8];
        #pragma unroll
        for (int rt = 0; rt < 4; ++rt)
            #pragma unroll
            for (int ct = 0; ct < 4; ++ct)
                acc[rt][ct] = __builtin_amdgcn_mfma_f32_16x16x32_bf16(
                    af[rt], bfr[ct], acc[rt][ct], 0, 0, 0);
        if (kt < 31) {
            store_tile_lds<AT>(As[cur ^ 1], t, ra);
            store_tile_lds<BT>(Bs[cur ^ 1], t, rb);
        }
        __syncthreads();
    }
    #pragma unroll
    for (int rt = 0; rt < 4; ++rt)
        #pragma unroll
        for (int ct = 0; ct < 4; ++ct)
            #pragma unroll
            for (int r = 0; r < 4; ++r) {
                int row = bm * 128 + wm + rt * 16 + lq * 4 + r;   // C-layout: row=(l>>4)*4+reg
                int col = bn * 128 + wn + ct * 16 + lrow;          //           col=l&15
                C[(size_t)row * ldc + col] = (CT)(acc[rt][ct][r] * scale);
            }
}

// ---------------- Causal flash attention ----------------
// q,k: (4096 x 1024) bf16, head h at cols [h*64, h*64+64)
// vt:  (1024 x 4096) bf16, row = h*64+d, col = b*2048+n  (V pre-transposed)
// Double-buffered K/V staging, one barrier per K-tile iteration.
__global__ __launch_bounds__(256) void attn_kernel(const __bf16* __restrict__ q,
                                                   const __bf16* __restrict__ kk,
                                                   const __bf16* __restrict__ vt,
                                                   __bf16* __restrict__ o) {
    int blk = blockIdx.x;
    int qt = blk & 31;
    int h = (blk >> 5) & 15;
    int b = blk >> 9;
    int rowbase = b * NSEQ;
    int t = threadIdx.x;
    int w = t >> 6, l = t & 63;
    int lrow = l & 15, lq = l >> 4;

    __shared__ __bf16 Kt[2][64 * 72];    // [j][d], stride 72
    __shared__ __bf16 Vs[2][64 * 72];    // [d][j], stride 72 (from pre-transposed vt)
    __shared__ __bf16 Ps[4 * 16 * 72];   // per-wave P strip, C-layout -> A-layout bounce
    __bf16* pw = &Ps[w * 16 * 72];

    const __bf16* kbase = kk + (size_t)rowbase * DIM + h * 64;
    const __bf16* vbase = vt + (size_t)(h * 64) * 4096 + b * 2048;

    // Q fragment (A-layout): m = l&15 -> q-row, k = (l>>4)*8+j
    const __bf16* qp = q + (size_t)(rowbase + qt * 64 + w * 16 + lrow) * DIM + h * 64;
    bf16x8 qa0 = *(const bf16x8*)(qp + lq * 8);
    bf16x8 qa1 = *(const bf16x8*)(qp + 32 + lq * 8);

    // staging: both K and V tiles are 64 rows x 64 cols, 2x16B per thread
    auto load_k = [&](int jt, uint4* r) {
        #pragma unroll
        for (int it = 0; it < 2; ++it) {
            int idx = t + it * 256;
            int row = idx >> 3;
            int c8 = (idx & 7) * 8;
            r[it] = *(const uint4*)(kbase + (size_t)(jt * 64 + row) * DIM + c8);
        }
    };
    auto load_v = [&](int jt, uint4* r) {
        #pragma unroll
        for (int it = 0; it < 2; ++it) {
            int idx = t + it * 256;
            int d = idx >> 3;
            int c8 = (idx & 7) * 8;
            r[it] = *(const uint4*)(vbase + (size_t)d * 4096 + jt * 64 + c8);
        }
    };
    auto store_tile = [&](__bf16* S, const uint4* r) {
        #pragma unroll
        for (int it = 0; it < 2; ++it) {
            int idx = t + it * 256;
            int row = idx >> 3;
            int c8 = (idx & 7) * 8;
            *(uint4*)&S[row * 72 + c8] = r[it];
        }
    };

    f32x4 oacc[4] = {};
    float m_r[4], l_r[4];
    #pragma unroll
    for (int r = 0; r < 4; ++r) { m_r[r] = -1e30f; l_r[r] = 0.0f; }

    uint4 kr[2], vr[2];
    load_k(0, kr); load_v(0, vr);
    store_tile(Kt[0], kr); store_tile(Vs[0], vr);
    __syncthreads();

    for (int jt = 0; jt <= qt; ++jt) {
        int cur = jt & 1;
        if (jt < qt) { load_k(jt + 1, kr); load_v(jt + 1, vr); }   // prefetch next tile

        // S strip (16 q-rows x 64 keys): B-op lane holds K[n=l&15][k=(l>>4)*8+j]
        f32x4 s[4];
        #pragma unroll
        for (int ct = 0; ct < 4; ++ct) {
            f32x4 z = {};
            bf16x8 kb0 = *(const bf16x8*)&Kt[cur][(ct * 16 + lrow) * 72 + lq * 8];
            bf16x8 kb1 = *(const bf16x8*)&Kt[cur][(ct * 16 + lrow) * 72 + 32 + lq * 8];
            z = __builtin_amdgcn_mfma_f32_16x16x32_bf16(qa0, kb0, z, 0, 0, 0);
            z = __builtin_amdgcn_mfma_f32_16x16x32_bf16(qa1, kb1, z, 0, 0, 0);
            s[ct] = z;
        }
        // causal mask on diagonal tile
        if (jt == qt) {
            #pragma unroll
            for (int ct = 0; ct < 4; ++ct)
                #pragma unroll
                for (int r = 0; r < 4; ++r) {
                    int col = ct * 16 + lrow;
                    int rw = w * 16 + lq * 4 + r;
                    if (col > rw) s[ct][r] = -3.0e38f;
                }
        }
        // online softmax; row (l>>4)*4+r replicated across a 16-lane group -> xor 1..8
        float alpha[4];
        #pragma unroll
        for (int r = 0; r < 4; ++r) {
            float mx = fmaxf(fmaxf(s[0][r], s[1][r]), fmaxf(s[2][r], s[3][r]));
            #pragma unroll
            for (int off = 8; off; off >>= 1) mx = fmaxf(mx, __shfl_xor(mx, off, 64));
            float mnew = fmaxf(m_r[r], mx);
            alpha[r] = __expf(m_r[r] - mnew);
            float ps = 0.0f;
            #pragma unroll
            for (int ct = 0; ct < 4; ++ct) {
                float p = __expf(s[ct][r] - mnew);
                s[ct][r] = p;
                ps += p;
            }
            #pragma unroll
            for (int off = 8; off; off >>= 1) ps += __shfl_xor(ps, off, 64);
            l_r[r] = l_r[r] * alpha[r] + ps;
            m_r[r] = mnew;
        }
        // P: C-layout -> LDS -> A-layout (per-wave private region, no barrier needed)
        #pragma unroll
        for (int ct = 0; ct < 4; ++ct)
            #pragma unroll
            for (int r = 0; r < 4; ++r)
                pw[(lq * 4 + r) * 72 + ct * 16 + lrow] = (__bf16)s[ct][r];
        // rescale O by alpha
        #pragma unroll
        for (int ct = 0; ct < 4; ++ct) {
            oacc[ct][0] *= alpha[0]; oacc[ct][1] *= alpha[1];
            oacc[ct][2] *= alpha[2]; oacc[ct][3] *= alpha[3];
        }
        // O += P @ V : A = P[m=i][k=j], B-frag lane holds V[k=j][n=d] from Vs[d][j]
        #pragma unroll
        for (int ch = 0; ch < 2; ++ch) {
            bf16x8 pa = *(const bf16x8*)&pw[lrow * 72 + ch * 32 + lq * 8];
            #pragma unroll
            for (int ct = 0; ct < 4; ++ct) {
                bf16x8 vb = *(const bf16x8*)&Vs[cur][(ct * 16 + lrow) * 72 + ch * 32 + lq * 8];
                oacc[ct] = __builtin_amdgcn_mfma_f32_16x16x32_bf16(pa, vb, oacc[ct], 0, 0, 0);
            }
        }
        if (jt < qt) {                       // write prefetched tile to alternate buffer
            store_tile(Kt[cur ^ 1], kr);
            store_tile(Vs[cur ^ 1], vr);
        }
        __syncthreads();
    }
    // epilogue: O /= l, write bf16
    #pragma unroll
    for (int ct = 0; ct < 4; ++ct)
        #pragma unroll
        for (int r = 0; r < 4; ++r) {
            int row = qt * 64 + w * 16 + lq * 4 + r;
            int col = ct * 16 + lrow;
            float val = oacc[ct][r] / l_r[r];
            o[(size_t)(rowbase + row) * DIM + h * 64 + col] = (__bf16)val;
        }
}

extern "C" void kernel_launch(void* const* d_in, const int* in_sizes, int n_in,
                              void* d_out, int out_size, void* d_ws, size_t ws_size,
                              hipStream_t stream) {
    const float* tokens = (const float*)d_in[0];
    const float* gamma  = (const float*)d_in[1];
    const float* wq = (const float*)d_in[2];
    const float* wk = (const float*)d_in[3];
    const float* wv = (const float*)d_in[4];
    const float* wo = (const float*)d_in[5];

    __bf16* ws  = (__bf16*)d_ws;
    __bf16* x   = ws;                           // 4096*1024 (dead after V^T GEMM)
    __bf16* qb  = x   + (size_t)4096 * 1024;
    __bf16* kb  = qb  + (size_t)4096 * 1024;
    __bf16* vtb = kb  + (size_t)4096 * 1024;    // V^T: 1024 x 4096
    __bf16* ao  = x;                            // alias: attn out reuses x's buffer
    float*  out = (float*)d_out;

    rmsnorm_kernel<<<4096, 256, 0, stream>>>(tokens, gamma, x);

    dim3 gg(32, 8);
    gemm_bt_kernel<__bf16, float, __bf16><<<gg, 256, 0, stream>>>(x, wq, qb, 0.125f, 1024);
    gemm_bt_kernel<__bf16, float, __bf16><<<gg, 256, 0, stream>>>(x, wk, kb, 1.0f, 1024);
    // V^T directly: C'[j,i] = sum_k wv[j,k] x[i,k]  ->  vt (1024 x 4096)
    dim3 gv(8, 32);
    gemm_bt_kernel<float, __bf16, __bf16><<<gv, 256, 0, stream>>>(wv, x, vtb, 1.0f, 4096);

    rope_kernel<<<8192, 256, 0, stream>>>(qb);
    rope_kernel<<<8192, 256, 0, stream>>>(kb);

    attn_kernel<<<1024, 256, 0, stream>>>(qb, kb, vtb, ao);

    gemm_bt_kernel<__bf16, float, float><<<gg, 256, 0, stream>>>(ao, wo, out, 1.0f, 1024);
}

// Round 6
// 365.844 us; speedup vs baseline: 1.1093x; 1.1093x over previous
//
#include <hip/hip_runtime.h>

typedef __bf16 bf16x8 __attribute__((ext_vector_type(8)));
typedef float f32x4 __attribute__((ext_vector_type(4)));

#define DIM 1024
#define NSEQ 2048

// ---------------- RMSNorm: fp32 in, bf16 out ----------------
__global__ __launch_bounds__(256) void rmsnorm_kernel(const float* __restrict__ x,
                                                      const float* __restrict__ g,
                                                      __bf16* __restrict__ o) {
    int row = blockIdx.x;
    int t = threadIdx.x;
    float4 xv = ((const float4*)(x + (size_t)row * DIM))[t];
    float ss = xv.x*xv.x + xv.y*xv.y + xv.z*xv.z + xv.w*xv.w;
    #pragma unroll
    for (int off = 32; off; off >>= 1) ss += __shfl_xor(ss, off, 64);
    __shared__ float red[4];
    if ((t & 63) == 0) red[t >> 6] = ss;
    __syncthreads();
    ss = red[0] + red[1] + red[2] + red[3];
    float r = rsqrtf(ss * (1.0f / 1024.0f) + 1.1920929e-07f);
    float4 gv = ((const float4*)g)[t];
    union { uint2 u; __bf16 h[4]; } p;
    p.h[0] = (__bf16)(xv.x * r * gv.x);
    p.h[1] = (__bf16)(xv.y * r * gv.y);
    p.h[2] = (__bf16)(xv.z * r * gv.z);
    p.h[3] = (__bf16)(xv.w * r * gv.w);
    *(uint2*)(o + (size_t)row * DIM + t * 4) = p.u;
}

// ---------------- RoPE in-place on (4096 x 1024) bf16, heads of 64 ----------------
__global__ __launch_bounds__(256) void rope_kernel(__bf16* __restrict__ x) {
    int gid = blockIdx.x * 256 + threadIdx.x;   // one pair per thread
    int row = gid >> 9;          // 512 pairs per row
    int pr = gid & 511;
    int pos = row & (NSEQ - 1);
    int dp = pr & 31;            // pair index within head
    float inv = __expf(-(float)dp * (9.210340371976184f / 32.0f)); // 10000^(-2dp/64)
    float ang = (float)pos * inv;
    float sn, cs;
    sincosf(ang, &sn, &cs);
    size_t off = (size_t)row * DIM + pr * 2;
    union { unsigned int u; __bf16 h[2]; } p;
    p.u = *(const unsigned int*)(x + off);
    float x1 = (float)p.h[0], x2 = (float)p.h[1];
    p.h[0] = (__bf16)(x1 * cs - x2 * sn);
    p.h[1] = (__bf16)(x2 * cs + x1 * sn);
    *(unsigned int*)(x + off) = p.u;
}

// ---------------- GEMM: C[i,j] = scale * sum_k A[i,k] * B[j,k] ----------------
// 512 threads (8 waves, 2x4 wave grid, 64x32 per wave), 128x128 tile, dbuf LDS.
#define LDT 40   // padded LDS stride (elements); 2-way-free banks

template <typename T>
__device__ __forceinline__ void load_tile_regs(const T* __restrict__ P, int base_row,
                                               int k0, int t, uint4* r) {
    if constexpr (sizeof(T) == 2) {
        int row = t >> 2, c8 = (t & 3) * 8;      // 512 x 16B = 128x32 bf16
        r[0] = *(const uint4*)((const __bf16*)P + (size_t)(base_row + row) * 1024 + k0 + c8);
    } else {
        #pragma unroll
        for (int it = 0; it < 2; ++it) {         // 1024 x 16B = 128x32 fp32
            int idx = t + it * 512;
            int row = idx >> 3, c4 = (idx & 7) * 4;
            r[it] = *(const uint4*)((const float*)P + (size_t)(base_row + row) * 1024 + k0 + c4);
        }
    }
}

template <typename T>
__device__ __forceinline__ void store_tile_lds(__bf16* S, int t, const uint4* r) {
    if constexpr (sizeof(T) == 2) {
        int row = t >> 2, c8 = (t & 3) * 8;
        *(uint4*)&S[row * LDT + c8] = r[0];
    } else {
        #pragma unroll
        for (int it = 0; it < 2; ++it) {
            int idx = t + it * 512;
            int row = idx >> 3, c4 = (idx & 7) * 4;
            union { uint4 q; float f[4]; } u; u.q = r[it];
            union { uint2 u2; __bf16 h[4]; } pk;
            pk.h[0] = (__bf16)u.f[0]; pk.h[1] = (__bf16)u.f[1];
            pk.h[2] = (__bf16)u.f[2]; pk.h[3] = (__bf16)u.f[3];
            *(uint2*)&S[row * LDT + c4] = pk.u2;
        }
    }
}

template <typename AT, typename BT, typename CT>
__global__ __launch_bounds__(512) void gemm_bt_kernel(const AT* __restrict__ A,
                                                      const BT* __restrict__ B,
                                                      CT* __restrict__ C,
                                                      float scale, int ldc) {
    __shared__ __bf16 As[2][128 * LDT];
    __shared__ __bf16 Bs[2][128 * LDT];
    int bm = blockIdx.x, bn = blockIdx.y;
    int t = threadIdx.x;
    int w = t >> 6, l = t & 63;
    int wm = (w >> 2) * 64, wn = (w & 3) * 32;   // 2x4 wave grid, 64x32 each
    int lrow = l & 15, lq = l >> 4;
    f32x4 acc[4][2] = {};
    uint4 ra[2], rb[2];

    load_tile_regs<AT>(A, bm * 128, 0, t, ra);
    load_tile_regs<BT>(B, bn * 128, 0, t, rb);
    store_tile_lds<AT>(As[0], t, ra);
    store_tile_lds<BT>(Bs[0], t, rb);
    __syncthreads();

    for (int kt = 0; kt < 32; ++kt) {
        int cur = kt & 1;
        if (kt < 31) {
            load_tile_regs<AT>(A, bm * 128, (kt + 1) * 32, t, ra);
            load_tile_regs<BT>(B, bn * 128, (kt + 1) * 32, t, rb);
        }
        bf16x8 af[4], bfr[2];
        #pragma unroll
        for (int i = 0; i < 4; ++i)
            af[i] = *(const bf16x8*)&As[cur][(wm + i * 16 + lrow) * LDT + lq * 8];
        #pragma unroll
        for (int j = 0; j < 2; ++j)
            bfr[j] = *(const bf16x8*)&Bs[cur][(wn + j * 16 + lrow) * LDT + lq * 8];
        #pragma unroll
        for (int i = 0; i < 4; ++i)
            #pragma unroll
            for (int j = 0; j < 2; ++j)
                acc[i][j] = __builtin_amdgcn_mfma_f32_16x16x32_bf16(
                    af[i], bfr[j], acc[i][j], 0, 0, 0);
        if (kt < 31) {
            store_tile_lds<AT>(As[cur ^ 1], t, ra);
            store_tile_lds<BT>(Bs[cur ^ 1], t, rb);
        }
        __syncthreads();
    }
    #pragma unroll
    for (int i = 0; i < 4; ++i)
        #pragma unroll
        for (int j = 0; j < 2; ++j)
            #pragma unroll
            for (int r = 0; r < 4; ++r) {
                int row = bm * 128 + wm + i * 16 + lq * 4 + r;   // C-layout
                int col = bn * 128 + wn + j * 16 + lrow;
                C[(size_t)row * ldc + col] = (CT)(acc[i][j][r] * scale);
            }
}

// ---------------- Causal flash attention (S^T formulation) ----------------
// q,k: (4096 x 1024) bf16, head h at cols [h*64, h*64+64)
// vt:  (1024 x 4096) bf16, row = h*64+d, col = b*2048+n  (V pre-transposed)
// S^T = K*Q^T: C-layout col = lane&15 = q-row -> per-lane softmax scalars,
// only 2 shuffles per reduction. O^T = V^T * P^T. Single-buffer LDS +
// register prefetch. qt reversed so long blocks dispatch first.
__global__ __launch_bounds__(256) void attn_kernel(const __bf16* __restrict__ q,
                                                   const __bf16* __restrict__ kk,
                                                   const __bf16* __restrict__ vt,
                                                   __bf16* __restrict__ o) {
    int blk = blockIdx.x;
    int qt = 31 - (blk & 31);            // long blocks first
    int h = (blk >> 5) & 15;
    int b = blk >> 9;
    int rowbase = b * NSEQ;
    int t = threadIdx.x;
    int w = t >> 6, l = t & 63;
    int lrow = l & 15, lq = l >> 4;

    __shared__ __bf16 Kt[64 * 72];       // [key][d], stride 72
    __shared__ __bf16 Vs[64 * 72];       // [d][key], stride 72 (from vt)
    __shared__ __bf16 Ps[4 * 16 * 72];   // per-wave P^T strip as [qrow][key]
    __bf16* pw = &Ps[w * 16 * 72];

    const __bf16* kbase = kk + (size_t)rowbase * DIM + h * 64;
    const __bf16* vbase = vt + (size_t)(h * 64) * 4096 + b * 2048;

    // Q as B-fragment: B[n=qrow=l&15][k=d=(l>>4)*8+j] — direct from global
    const __bf16* qp = q + (size_t)(rowbase + qt * 64 + w * 16 + lrow) * DIM + h * 64;
    bf16x8 qb0 = *(const bf16x8*)(qp + lq * 8);
    bf16x8 qb1 = *(const bf16x8*)(qp + 32 + lq * 8);

    auto load_k = [&](int jt, uint4* r) {
        #pragma unroll
        for (int it = 0; it < 2; ++it) {
            int idx = t + it * 256;
            int row = idx >> 3, c8 = (idx & 7) * 8;
            r[it] = *(const uint4*)(kbase + (size_t)(jt * 64 + row) * DIM + c8);
        }
    };
    auto load_v = [&](int jt, uint4* r) {
        #pragma unroll
        for (int it = 0; it < 2; ++it) {
            int idx = t + it * 256;
            int d = idx >> 3, c8 = (idx & 7) * 8;
            r[it] = *(const uint4*)(vbase + (size_t)d * 4096 + jt * 64 + c8);
        }
    };
    auto store_tile = [&](__bf16* S, const uint4* r) {
        #pragma unroll
        for (int it = 0; it < 2; ++it) {
            int idx = t + it * 256;
            int row = idx >> 3, c8 = (idx & 7) * 8;
            *(uint4*)&S[row * 72 + c8] = r[it];
        }
    };

    f32x4 oacc[4] = {};                  // O^T: [d-chunk][d-reg], col = qrow
    float m_r = -1e30f, l_r = 0.0f;      // per-lane scalars (qrow = lrow)

    uint4 kr[2], vr[2];
    load_k(0, kr); load_v(0, vr);
    store_tile(Kt, kr); store_tile(Vs, vr);
    __syncthreads();

    for (int jt = 0; jt <= qt; ++jt) {
        if (jt < qt) { load_k(jt + 1, kr); load_v(jt + 1, vr); }   // reg prefetch

        // S^T strip (64 keys x 16 qrows): A = K[m=key][k=d], B = Q
        f32x4 st[4];
        #pragma unroll
        for (int ct = 0; ct < 4; ++ct) {
            f32x4 z = {};
            bf16x8 ka0 = *(const bf16x8*)&Kt[(ct * 16 + lrow) * 72 + lq * 8];
            bf16x8 ka1 = *(const bf16x8*)&Kt[(ct * 16 + lrow) * 72 + 32 + lq * 8];
            z = __builtin_amdgcn_mfma_f32_16x16x32_bf16(ka0, qb0, z, 0, 0, 0);
            z = __builtin_amdgcn_mfma_f32_16x16x32_bf16(ka1, qb1, z, 0, 0, 0);
            st[ct] = z;   // key = ct*16 + lq*4 + r, qrow(local) = lrow
        }
        // causal mask on diagonal tile: key_local > qrow_local
        if (jt == qt) {
            int qr = w * 16 + lrow;
            #pragma unroll
            for (int ct = 0; ct < 4; ++ct)
                #pragma unroll
                for (int r = 0; r < 4; ++r)
                    if (ct * 16 + lq * 4 + r > qr) st[ct][r] = -3.0e38f;
        }
        // per-lane online softmax (16 keys in-lane, 2 shuffles across lane groups)
        float mx = st[0][0];
        #pragma unroll
        for (int ct = 0; ct < 4; ++ct)
            #pragma unroll
            for (int r = 0; r < 4; ++r) mx = fmaxf(mx, st[ct][r]);
        mx = fmaxf(mx, __shfl_xor(mx, 16, 64));
        mx = fmaxf(mx, __shfl_xor(mx, 32, 64));
        float mnew = fmaxf(m_r, mx);
        float alpha = __expf(m_r - mnew);
        float ps = 0.0f;
        #pragma unroll
        for (int ct = 0; ct < 4; ++ct)
            #pragma unroll
            for (int r = 0; r < 4; ++r) {
                float p = __expf(st[ct][r] - mnew);
                st[ct][r] = p;
                ps += p;
            }
        ps += __shfl_xor(ps, 16, 64);
        ps += __shfl_xor(ps, 32, 64);
        l_r = l_r * alpha + ps;
        m_r = mnew;

        // P^T -> LDS as [qrow][key] row-major (per-wave strip, no barrier)
        #pragma unroll
        for (int ct = 0; ct < 4; ++ct)
            #pragma unroll
            for (int r = 0; r < 4; ++r)
                pw[lrow * 72 + ct * 16 + lq * 4 + r] = (__bf16)st[ct][r];
        // rescale O^T by per-lane alpha
        #pragma unroll
        for (int ct = 0; ct < 4; ++ct)
            #pragma unroll
            for (int r = 0; r < 4; ++r) oacc[ct][r] *= alpha;
        // O^T += V^T * P^T: A = V^T[m=d][k=key] from Vs, B = P^T[n=qrow][k=key]
        bf16x8 pb0 = *(const bf16x8*)&pw[lrow * 72 + lq * 8];
        bf16x8 pb1 = *(const bf16x8*)&pw[lrow * 72 + 32 + lq * 8];
        #pragma unroll
        for (int ct = 0; ct < 4; ++ct) {
            bf16x8 va0 = *(const bf16x8*)&Vs[(ct * 16 + lrow) * 72 + lq * 8];
            bf16x8 va1 = *(const bf16x8*)&Vs[(ct * 16 + lrow) * 72 + 32 + lq * 8];
            oacc[ct] = __builtin_amdgcn_mfma_f32_16x16x32_bf16(va0, pb0, oacc[ct], 0, 0, 0);
            oacc[ct] = __builtin_amdgcn_mfma_f32_16x16x32_bf16(va1, pb1, oacc[ct], 0, 0, 0);
        }
        __syncthreads();                 // all waves done reading Kt/Vs
        if (jt < qt) {
            store_tile(Kt, kr);          // overwrite with prefetched tile
            store_tile(Vs, vr);
        }
        __syncthreads();
    }
    // epilogue: O^T C-layout -> o[qrow][d]; lane writes 4 consecutive d per chunk
    float rcp = 1.0f / l_r;
    const size_t orow = (size_t)(rowbase + qt * 64 + w * 16 + lrow) * DIM + h * 64;
    #pragma unroll
    for (int ct = 0; ct < 4; ++ct) {
        union { uint2 u; __bf16 h4[4]; } pk;
        #pragma unroll
        for (int r = 0; r < 4; ++r) pk.h4[r] = (__bf16)(oacc[ct][r] * rcp);
        *(uint2*)(o + orow + ct * 16 + lq * 4) = pk.u;
    }
}

extern "C" void kernel_launch(void* const* d_in, const int* in_sizes, int n_in,
                              void* d_out, int out_size, void* d_ws, size_t ws_size,
                              hipStream_t stream) {
    const float* tokens = (const float*)d_in[0];
    const float* gamma  = (const float*)d_in[1];
    const float* wq = (const float*)d_in[2];
    const float* wk = (const float*)d_in[3];
    const float* wv = (const float*)d_in[4];
    const float* wo = (const float*)d_in[5];

    __bf16* ws  = (__bf16*)d_ws;
    __bf16* x   = ws;                           // 4096*1024 (dead after V^T GEMM)
    __bf16* qb  = x   + (size_t)4096 * 1024;
    __bf16* kb  = qb  + (size_t)4096 * 1024;
    __bf16* vtb = kb  + (size_t)4096 * 1024;    // V^T: 1024 x 4096
    __bf16* ao  = x;                            // alias: attn out reuses x's buffer
    float*  out = (float*)d_out;

    rmsnorm_kernel<<<4096, 256, 0, stream>>>(tokens, gamma, x);

    dim3 gg(32, 8);
    gemm_bt_kernel<__bf16, float, __bf16><<<gg, 512, 0, stream>>>(x, wq, qb, 0.125f, 1024);
    gemm_bt_kernel<__bf16, float, __bf16><<<gg, 512, 0, stream>>>(x, wk, kb, 1.0f, 1024);
    // V^T directly: C'[j,i] = sum_k wv[j,k] x[i,k]  ->  vt (1024 x 4096)
    dim3 gv(8, 32);
    gemm_bt_kernel<float, __bf16, __bf16><<<gv, 512, 0, stream>>>(wv, x, vtb, 1.0f, 4096);

    rope_kernel<<<8192, 256, 0, stream>>>(qb);
    rope_kernel<<<8192, 256, 0, stream>>>(kb);

    attn_kernel<<<1024, 256, 0, stream>>>(qb, kb, vtb, ao);

    gemm_bt_kernel<__bf16, float, float><<<gg, 512, 0, stream>>>(ao, wo, out, 1.0f, 1024);
}

// Round 7
// 355.187 us; speedup vs baseline: 1.1426x; 1.0300x over previous
//
#include <hip/hip_runtime.h>

typedef __bf16 bf16x8 __attribute__((ext_vector_type(8)));
typedef float f32x4 __attribute__((ext_vector_type(4)));

#define DIM 1024
#define NSEQ 2048

// ---------------- RMSNorm: fp32 in, bf16 out ----------------
__global__ __launch_bounds__(256) void rmsnorm_kernel(const float* __restrict__ x,
                                                      const float* __restrict__ g,
                                                      __bf16* __restrict__ o) {
    int row = blockIdx.x;
    int t = threadIdx.x;
    float4 xv = ((const float4*)(x + (size_t)row * DIM))[t];
    float ss = xv.x*xv.x + xv.y*xv.y + xv.z*xv.z + xv.w*xv.w;
    #pragma unroll
    for (int off = 32; off; off >>= 1) ss += __shfl_xor(ss, off, 64);
    __shared__ float red[4];
    if ((t & 63) == 0) red[t >> 6] = ss;
    __syncthreads();
    ss = red[0] + red[1] + red[2] + red[3];
    float r = rsqrtf(ss * (1.0f / 1024.0f) + 1.1920929e-07f);
    float4 gv = ((const float4*)g)[t];
    union { uint2 u; __bf16 h[4]; } p;
    p.h[0] = (__bf16)(xv.x * r * gv.x);
    p.h[1] = (__bf16)(xv.y * r * gv.y);
    p.h[2] = (__bf16)(xv.z * r * gv.z);
    p.h[3] = (__bf16)(xv.w * r * gv.w);
    *(uint2*)(o + (size_t)row * DIM + t * 4) = p.u;
}

// ---------------- RoPE in-place on (4096 x 1024) bf16, heads of 64 ----------------
__global__ __launch_bounds__(256) void rope_kernel(__bf16* __restrict__ x) {
    int gid = blockIdx.x * 256 + threadIdx.x;   // one pair per thread
    int row = gid >> 9;          // 512 pairs per row
    int pr = gid & 511;
    int pos = row & (NSEQ - 1);
    int dp = pr & 31;            // pair index within head
    float inv = __expf(-(float)dp * (9.210340371976184f / 32.0f)); // 10000^(-2dp/64)
    float ang = (float)pos * inv;
    float sn, cs;
    sincosf(ang, &sn, &cs);
    size_t off = (size_t)row * DIM + pr * 2;
    union { unsigned int u; __bf16 h[2]; } p;
    p.u = *(const unsigned int*)(x + off);
    float x1 = (float)p.h[0], x2 = (float)p.h[1];
    p.h[0] = (__bf16)(x1 * cs - x2 * sn);
    p.h[1] = (__bf16)(x2 * cs + x1 * sn);
    *(unsigned int*)(x + off) = p.u;
}

// ---------------- GEMM: C[i,j] = scale * sum_k A[i,k] * B[j,k] ----------------
// 256 threads (4 waves, 2x2 grid, 64x64 per wave), 128x128 tile, dbuf LDS +
// register prefetch. launch_bounds(256,2) keeps prefetch regs out of scratch.
#define LDT 40   // padded LDS stride (elements); 2-way-free banks

template <typename T>
__device__ __forceinline__ void load_tile_regs(const T* __restrict__ P, int base_row,
                                               int k0, int t, uint4* r) {
    if constexpr (sizeof(T) == 2) {
        #pragma unroll
        for (int it = 0; it < 2; ++it) {
            int idx = t + it * 256;          // 512 x 16B covers 128x32 bf16
            int row = idx >> 2;
            int c8 = (idx & 3) * 8;
            r[it] = *(const uint4*)((const __bf16*)P + (size_t)(base_row + row) * 1024 + k0 + c8);
        }
    } else {
        #pragma unroll
        for (int it = 0; it < 4; ++it) {
            int idx = t + it * 256;          // 1024 x 16B covers 128x32 fp32
            int row = idx >> 3;
            int c4 = (idx & 7) * 4;
            r[it] = *(const uint4*)((const float*)P + (size_t)(base_row + row) * 1024 + k0 + c4);
        }
    }
}

template <typename T>
__device__ __forceinline__ void store_tile_lds(__bf16* S, int t, const uint4* r) {
    if constexpr (sizeof(T) == 2) {
        #pragma unroll
        for (int it = 0; it < 2; ++it) {
            int idx = t + it * 256;
            int row = idx >> 2;
            int c8 = (idx & 3) * 8;
            *(uint4*)&S[row * LDT + c8] = r[it];
        }
    } else {
        #pragma unroll
        for (int it = 0; it < 4; ++it) {
            int idx = t + it * 256;
            int row = idx >> 3;
            int c4 = (idx & 7) * 4;
            union { uint4 q; float f[4]; } u; u.q = r[it];
            union { uint2 u2; __bf16 h[4]; } pk;
            pk.h[0] = (__bf16)u.f[0]; pk.h[1] = (__bf16)u.f[1];
            pk.h[2] = (__bf16)u.f[2]; pk.h[3] = (__bf16)u.f[3];
            *(uint2*)&S[row * LDT + c4] = pk.u2;
        }
    }
}

template <typename AT, typename BT, typename CT>
__global__ __launch_bounds__(256, 2) void gemm_bt_kernel(const AT* __restrict__ A,
                                                         const BT* __restrict__ B,
                                                         CT* __restrict__ C,
                                                         float scale, int ldc) {
    __shared__ __bf16 As[2][128 * LDT];
    __shared__ __bf16 Bs[2][128 * LDT];
    int bm = blockIdx.x, bn = blockIdx.y;
    int t = threadIdx.x;
    int w = t >> 6, l = t & 63;
    int wm = (w >> 1) * 64, wn = (w & 1) * 64;   // wave 2x2 grid, each 64x64
    int lrow = l & 15, lq = l >> 4;
    f32x4 acc[4][4] = {};
    uint4 ra[sizeof(AT)], rb[sizeof(BT)];        // 2 (bf16) or 4 (fp32) regs used

    load_tile_regs<AT>(A, bm * 128, 0, t, ra);
    load_tile_regs<BT>(B, bn * 128, 0, t, rb);
    store_tile_lds<AT>(As[0], t, ra);
    store_tile_lds<BT>(Bs[0], t, rb);
    __syncthreads();

    for (int kt = 0; kt < 32; ++kt) {
        int cur = kt & 1;
        if (kt < 31) {
            load_tile_regs<AT>(A, bm * 128, (kt + 1) * 32, t, ra);
            load_tile_regs<BT>(B, bn * 128, (kt + 1) * 32, t, rb);
        }
        bf16x8 af[4], bfr[4];
        #pragma unroll
        for (int i = 0; i < 4; ++i)
            af[i] = *(const bf16x8*)&As[cur][(wm + i * 16 + lrow) * LDT + lq * 8];
        #pragma unroll
        for (int i = 0; i < 4; ++i)
            bfr[i] = *(const bf16x8*)&Bs[cur][(wn + i * 16 + lrow) * LDT + lq * 8];
        #pragma unroll
        for (int rt = 0; rt < 4; ++rt)
            #pragma unroll
            for (int ct = 0; ct < 4; ++ct)
                acc[rt][ct] = __builtin_amdgcn_mfma_f32_16x16x32_bf16(
                    af[rt], bfr[ct], acc[rt][ct], 0, 0, 0);
        if (kt < 31) {
            store_tile_lds<AT>(As[cur ^ 1], t, ra);
            store_tile_lds<BT>(Bs[cur ^ 1], t, rb);
        }
        __syncthreads();
    }
    #pragma unroll
    for (int rt = 0; rt < 4; ++rt)
        #pragma unroll
        for (int ct = 0; ct < 4; ++ct)
            #pragma unroll
            for (int r = 0; r < 4; ++r) {
                int row = bm * 128 + wm + rt * 16 + lq * 4 + r;   // C-layout
                int col = bn * 128 + wn + ct * 16 + lrow;
                C[(size_t)row * ldc + col] = (CT)(acc[rt][ct][r] * scale);
            }
}

// ---------------- Causal flash attention (S^T formulation) ----------------
// q,k: (4096 x 1024) bf16, head h at cols [h*64, h*64+64)
// vt:  (1024 x 4096) bf16, row = h*64+d, col = b*2048+n  (V pre-transposed)
// S^T = K*Q^T: C-layout col = lane&15 = q-row -> per-lane softmax scalars.
// O^T = V^T * P^T. Single-buffer LDS + register prefetch.
// launch_bounds(256,4): 128-VGPR budget so prefetch regs don't spill.
__global__ __launch_bounds__(256, 4) void attn_kernel(const __bf16* __restrict__ q,
                                                      const __bf16* __restrict__ kk,
                                                      const __bf16* __restrict__ vt,
                                                      __bf16* __restrict__ o) {
    int blk = blockIdx.x;
    int qt = 31 - (blk & 31);            // long blocks first
    int h = (blk >> 5) & 15;
    int b = blk >> 9;
    int rowbase = b * NSEQ;
    int t = threadIdx.x;
    int w = t >> 6, l = t & 63;
    int lrow = l & 15, lq = l >> 4;

    __shared__ __bf16 Kt[64 * 72];       // [key][d], stride 72
    __shared__ __bf16 Vs[64 * 72];       // [d][key], stride 72 (from vt)
    __shared__ __bf16 Ps[4 * 16 * 72];   // per-wave P^T strip as [qrow][key]
    __bf16* pw = &Ps[w * 16 * 72];

    const __bf16* kbase = kk + (size_t)rowbase * DIM + h * 64;
    const __bf16* vbase = vt + (size_t)(h * 64) * 4096 + b * 2048;

    // Q as B-fragment: B[n=qrow=l&15][k=d=(l>>4)*8+j] — direct from global
    const __bf16* qp = q + (size_t)(rowbase + qt * 64 + w * 16 + lrow) * DIM + h * 64;
    bf16x8 qb0 = *(const bf16x8*)(qp + lq * 8);
    bf16x8 qb1 = *(const bf16x8*)(qp + 32 + lq * 8);

    auto load_k = [&](int jt, uint4* r) {
        #pragma unroll
        for (int it = 0; it < 2; ++it) {
            int idx = t + it * 256;
            int row = idx >> 3, c8 = (idx & 7) * 8;
            r[it] = *(const uint4*)(kbase + (size_t)(jt * 64 + row) * DIM + c8);
        }
    };
    auto load_v = [&](int jt, uint4* r) {
        #pragma unroll
        for (int it = 0; it < 2; ++it) {
            int idx = t + it * 256;
            int d = idx >> 3, c8 = (idx & 7) * 8;
            r[it] = *(const uint4*)(vbase + (size_t)d * 4096 + jt * 64 + c8);
        }
    };
    auto store_tile = [&](__bf16* S, const uint4* r) {
        #pragma unroll
        for (int it = 0; it < 2; ++it) {
            int idx = t + it * 256;
            int row = idx >> 3, c8 = (idx & 7) * 8;
            *(uint4*)&S[row * 72 + c8] = r[it];
        }
    };

    f32x4 oacc[4] = {};                  // O^T: [d-chunk][d-reg], col = qrow
    float m_r = -1e30f, l_r = 0.0f;      // per-lane scalars (qrow = lrow)

    uint4 kr[2], vr[2];
    load_k(0, kr); load_v(0, vr);
    store_tile(Kt, kr); store_tile(Vs, vr);
    __syncthreads();

    for (int jt = 0; jt <= qt; ++jt) {
        if (jt < qt) { load_k(jt + 1, kr); load_v(jt + 1, vr); }   // reg prefetch

        // S^T strip (64 keys x 16 qrows): A = K[m=key][k=d], B = Q
        f32x4 st[4];
        #pragma unroll
        for (int ct = 0; ct < 4; ++ct) {
            f32x4 z = {};
            bf16x8 ka0 = *(const bf16x8*)&Kt[(ct * 16 + lrow) * 72 + lq * 8];
            bf16x8 ka1 = *(const bf16x8*)&Kt[(ct * 16 + lrow) * 72 + 32 + lq * 8];
            z = __builtin_amdgcn_mfma_f32_16x16x32_bf16(ka0, qb0, z, 0, 0, 0);
            z = __builtin_amdgcn_mfma_f32_16x16x32_bf16(ka1, qb1, z, 0, 0, 0);
            st[ct] = z;   // key = ct*16 + lq*4 + r, qrow(local) = lrow
        }
        // causal mask on diagonal tile: key_local > qrow_local
        if (jt == qt) {
            int qr = w * 16 + lrow;
            #pragma unroll
            for (int ct = 0; ct < 4; ++ct)
                #pragma unroll
                for (int r = 0; r < 4; ++r)
                    if (ct * 16 + lq * 4 + r > qr) st[ct][r] = -3.0e38f;
        }
        // per-lane online softmax (16 keys in-lane, 2 shuffles across lane groups)
        float mx = st[0][0];
        #pragma unroll
        for (int ct = 0; ct < 4; ++ct)
            #pragma unroll
            for (int r = 0; r < 4; ++r) mx = fmaxf(mx, st[ct][r]);
        mx = fmaxf(mx, __shfl_xor(mx, 16, 64));
        mx = fmaxf(mx, __shfl_xor(mx, 32, 64));
        float mnew = fmaxf(m_r, mx);
        float alpha = __expf(m_r - mnew);
        float ps = 0.0f;
        #pragma unroll
        for (int ct = 0; ct < 4; ++ct)
            #pragma unroll
            for (int r = 0; r < 4; ++r) {
                float p = __expf(st[ct][r] - mnew);
                st[ct][r] = p;
                ps += p;
            }
        ps += __shfl_xor(ps, 16, 64);
        ps += __shfl_xor(ps, 32, 64);
        l_r = l_r * alpha + ps;
        m_r = mnew;

        // P^T -> LDS as [qrow][key] row-major (per-wave strip, no barrier)
        #pragma unroll
        for (int ct = 0; ct < 4; ++ct)
            #pragma unroll
            for (int r = 0; r < 4; ++r)
                pw[lrow * 72 + ct * 16 + lq * 4 + r] = (__bf16)st[ct][r];
        // rescale O^T by per-lane alpha
        #pragma unroll
        for (int ct = 0; ct < 4; ++ct)
            #pragma unroll
            for (int r = 0; r < 4; ++r) oacc[ct][r] *= alpha;
        // O^T += V^T * P^T: A = V^T[m=d][k=key] from Vs, B = P^T[n=qrow][k=key]
        bf16x8 pb0 = *(const bf16x8*)&pw[lrow * 72 + lq * 8];
        bf16x8 pb1 = *(const bf16x8*)&pw[lrow * 72 + 32 + lq * 8];
        #pragma unroll
        for (int ct = 0; ct < 4; ++ct) {
            bf16x8 va0 = *(const bf16x8*)&Vs[(ct * 16 + lrow) * 72 + lq * 8];
            bf16x8 va1 = *(const bf16x8*)&Vs[(ct * 16 + lrow) * 72 + 32 + lq * 8];
            oacc[ct] = __builtin_amdgcn_mfma_f32_16x16x32_bf16(va0, pb0, oacc[ct], 0, 0, 0);
            oacc[ct] = __builtin_amdgcn_mfma_f32_16x16x32_bf16(va1, pb1, oacc[ct], 0, 0, 0);
        }
        __syncthreads();                 // all waves done reading Kt/Vs
        if (jt < qt) {
            store_tile(Kt, kr);          // overwrite with prefetched tile
            store_tile(Vs, vr);
        }
        __syncthreads();
    }
    // epilogue: O^T C-layout -> o[qrow][d]; lane writes 4 consecutive d per chunk
    float rcp = 1.0f / l_r;
    const size_t orow = (size_t)(rowbase + qt * 64 + w * 16 + lrow) * DIM + h * 64;
    #pragma unroll
    for (int ct = 0; ct < 4; ++ct) {
        union { uint2 u; __bf16 h4[4]; } pk;
        #pragma unroll
        for (int r = 0; r < 4; ++r) pk.h4[r] = (__bf16)(oacc[ct][r] * rcp);
        *(uint2*)(o + orow + ct * 16 + lq * 4) = pk.u;
    }
}

extern "C" void kernel_launch(void* const* d_in, const int* in_sizes, int n_in,
                              void* d_out, int out_size, void* d_ws, size_t ws_size,
                              hipStream_t stream) {
    const float* tokens = (const float*)d_in[0];
    const float* gamma  = (const float*)d_in[1];
    const float* wq = (const float*)d_in[2];
    const float* wk = (const float*)d_in[3];
    const float* wv = (const float*)d_in[4];
    const float* wo = (const float*)d_in[5];

    __bf16* ws  = (__bf16*)d_ws;
    __bf16* x   = ws;                           // 4096*1024 (dead after V^T GEMM)
    __bf16* qb  = x   + (size_t)4096 * 1024;
    __bf16* kb  = qb  + (size_t)4096 * 1024;
    __bf16* vtb = kb  + (size_t)4096 * 1024;    // V^T: 1024 x 4096
    __bf16* ao  = x;                            // alias: attn out reuses x's buffer
    float*  out = (float*)d_out;

    rmsnorm_kernel<<<4096, 256, 0, stream>>>(tokens, gamma, x);

    dim3 gg(32, 8);
    gemm_bt_kernel<__bf16, float, __bf16><<<gg, 256, 0, stream>>>(x, wq, qb, 0.125f, 1024);
    gemm_bt_kernel<__bf16, float, __bf16><<<gg, 256, 0, stream>>>(x, wk, kb, 1.0f, 1024);
    // V^T directly: C'[j,i] = sum_k wv[j,k] x[i,k]  ->  vt (1024 x 4096)
    dim3 gv(8, 32);
    gemm_bt_kernel<float, __bf16, __bf16><<<gv, 256, 0, stream>>>(wv, x, vtb, 1.0f, 4096);

    rope_kernel<<<8192, 256, 0, stream>>>(qb);
    rope_kernel<<<8192, 256, 0, stream>>>(kb);

    attn_kernel<<<1024, 256, 0, stream>>>(qb, kb, vtb, ao);

    gemm_bt_kernel<__bf16, float, float><<<gg, 256, 0, stream>>>(ao, wo, out, 1.0f, 1024);
}

// Round 8
// 257.349 us; speedup vs baseline: 1.5769x; 1.3802x over previous
//
#include <hip/hip_runtime.h>

typedef __bf16 bf16x8 __attribute__((ext_vector_type(8)));
typedef float f32x4 __attribute__((ext_vector_type(4)));

#define DIM 1024
#define NSEQ 2048

// ---------------- RMSNorm: fp32 in, bf16 out ----------------
__global__ __launch_bounds__(256) void rmsnorm_kernel(const float* __restrict__ x,
                                                      const float* __restrict__ g,
                                                      __bf16* __restrict__ o) {
    int row = blockIdx.x;
    int t = threadIdx.x;
    float4 xv = ((const float4*)(x + (size_t)row * DIM))[t];
    float ss = xv.x*xv.x + xv.y*xv.y + xv.z*xv.z + xv.w*xv.w;
    #pragma unroll
    for (int off = 32; off; off >>= 1) ss += __shfl_xor(ss, off, 64);
    __shared__ float red[4];
    if ((t & 63) == 0) red[t >> 6] = ss;
    __syncthreads();
    ss = red[0] + red[1] + red[2] + red[3];
    float r = rsqrtf(ss * (1.0f / 1024.0f) + 1.1920929e-07f);
    float4 gv = ((const float4*)g)[t];
    union { uint2 u; __bf16 h[4]; } p;
    p.h[0] = (__bf16)(xv.x * r * gv.x);
    p.h[1] = (__bf16)(xv.y * r * gv.y);
    p.h[2] = (__bf16)(xv.z * r * gv.z);
    p.h[3] = (__bf16)(xv.w * r * gv.w);
    *(uint2*)(o + (size_t)row * DIM + t * 4) = p.u;
}

// ---------------- RoPE in-place on (4096 x 1024) bf16, heads of 64 ----------------
__global__ __launch_bounds__(256) void rope_kernel(__bf16* __restrict__ x) {
    int gid = blockIdx.x * 256 + threadIdx.x;   // one pair per thread
    int row = gid >> 9;          // 512 pairs per row
    int pr = gid & 511;
    int pos = row & (NSEQ - 1);
    int dp = pr & 31;            // pair index within head
    float inv = __expf(-(float)dp * (9.210340371976184f / 32.0f)); // 10000^(-2dp/64)
    float ang = (float)pos * inv;
    float sn, cs;
    sincosf(ang, &sn, &cs);
    size_t off = (size_t)row * DIM + pr * 2;
    union { unsigned int u; __bf16 h[2]; } p;
    p.u = *(const unsigned int*)(x + off);
    float x1 = (float)p.h[0], x2 = (float)p.h[1];
    p.h[0] = (__bf16)(x1 * cs - x2 * sn);
    p.h[1] = (__bf16)(x2 * cs + x1 * sn);
    *(unsigned int*)(x + off) = p.u;
}

// ---------------- GEMM: C[i,j] = scale * sum_k A[i,k] * B[j,k] ----------------
// 256 threads (4 waves, 2x2 grid, 64x64 per wave), 128x128 tile, dbuf LDS +
// register prefetch. Plain launch_bounds(256) — round-5 measured-best config.
#define LDT 40   // padded LDS stride (elements); 2-way-free banks

template <typename T>
__device__ __forceinline__ void load_tile_regs(const T* __restrict__ P, int base_row,
                                               int k0, int t, uint4* r) {
    if constexpr (sizeof(T) == 2) {
        #pragma unroll
        for (int it = 0; it < 2; ++it) {
            int idx = t + it * 256;          // 512 x 16B covers 128x32 bf16
            int row = idx >> 2;
            int c8 = (idx & 3) * 8;
            r[it] = *(const uint4*)((const __bf16*)P + (size_t)(base_row + row) * 1024 + k0 + c8);
        }
    } else {
        #pragma unroll
        for (int it = 0; it < 4; ++it) {
            int idx = t + it * 256;          // 1024 x 16B covers 128x32 fp32
            int row = idx >> 3;
            int c4 = (idx & 7) * 4;
            r[it] = *(const uint4*)((const float*)P + (size_t)(base_row + row) * 1024 + k0 + c4);
        }
    }
}

template <typename T>
__device__ __forceinline__ void store_tile_lds(__bf16* S, int t, const uint4* r) {
    if constexpr (sizeof(T) == 2) {
        #pragma unroll
        for (int it = 0; it < 2; ++it) {
            int idx = t + it * 256;
            int row = idx >> 2;
            int c8 = (idx & 3) * 8;
            *(uint4*)&S[row * LDT + c8] = r[it];
        }
    } else {
        #pragma unroll
        for (int it = 0; it < 4; ++it) {
            int idx = t + it * 256;
            int row = idx >> 3;
            int c4 = (idx & 7) * 4;
            union { uint4 q; float f[4]; } u; u.q = r[it];
            union { uint2 u2; __bf16 h[4]; } pk;
            pk.h[0] = (__bf16)u.f[0]; pk.h[1] = (__bf16)u.f[1];
            pk.h[2] = (__bf16)u.f[2]; pk.h[3] = (__bf16)u.f[3];
            *(uint2*)&S[row * LDT + c4] = pk.u2;
        }
    }
}

template <typename AT, typename BT, typename CT>
__global__ __launch_bounds__(256) void gemm_bt_kernel(const AT* __restrict__ A,
                                                      const BT* __restrict__ B,
                                                      CT* __restrict__ C,
                                                      float scale, int ldc) {
    __shared__ __bf16 As[2][128 * LDT];
    __shared__ __bf16 Bs[2][128 * LDT];
    int bm = blockIdx.x, bn = blockIdx.y;
    int t = threadIdx.x;
    int w = t >> 6, l = t & 63;
    int wm = (w >> 1) * 64, wn = (w & 1) * 64;   // wave 2x2 grid, each 64x64
    int lrow = l & 15, lq = l >> 4;
    f32x4 acc[4][4] = {};
    uint4 ra[sizeof(AT)], rb[sizeof(BT)];        // 2 (bf16) or 4 (fp32) regs used

    load_tile_regs<AT>(A, bm * 128, 0, t, ra);
    load_tile_regs<BT>(B, bn * 128, 0, t, rb);
    store_tile_lds<AT>(As[0], t, ra);
    store_tile_lds<BT>(Bs[0], t, rb);
    __syncthreads();

    for (int kt = 0; kt < 32; ++kt) {
        int cur = kt & 1;
        if (kt < 31) {
            load_tile_regs<AT>(A, bm * 128, (kt + 1) * 32, t, ra);
            load_tile_regs<BT>(B, bn * 128, (kt + 1) * 32, t, rb);
        }
        bf16x8 af[4], bfr[4];
        #pragma unroll
        for (int i = 0; i < 4; ++i)
            af[i] = *(const bf16x8*)&As[cur][(wm + i * 16 + lrow) * LDT + lq * 8];
        #pragma unroll
        for (int i = 0; i < 4; ++i)
            bfr[i] = *(const bf16x8*)&Bs[cur][(wn + i * 16 + lrow) * LDT + lq * 8];
        #pragma unroll
        for (int rt = 0; rt < 4; ++rt)
            #pragma unroll
            for (int ct = 0; ct < 4; ++ct)
                acc[rt][ct] = __builtin_amdgcn_mfma_f32_16x16x32_bf16(
                    af[rt], bfr[ct], acc[rt][ct], 0, 0, 0);
        if (kt < 31) {
            store_tile_lds<AT>(As[cur ^ 1], t, ra);
            store_tile_lds<BT>(Bs[cur ^ 1], t, rb);
        }
        __syncthreads();
    }
    #pragma unroll
    for (int rt = 0; rt < 4; ++rt)
        #pragma unroll
        for (int ct = 0; ct < 4; ++ct)
            #pragma unroll
            for (int r = 0; r < 4; ++r) {
                int row = bm * 128 + wm + rt * 16 + lq * 4 + r;   // C-layout
                int col = bn * 128 + wn + ct * 16 + lrow;
                C[(size_t)row * ldc + col] = (CT)(acc[rt][ct][r] * scale);
            }
}

// ---------------- Causal flash attention (S^T formulation) ----------------
// q,k: (4096 x 1024) bf16, head h at cols [h*64, h*64+64)
// vt:  (1024 x 4096) bf16, row = h*64+d, col = b*2048+n  (V pre-transposed)
// S^T = K*Q^T: C-layout col = lane&15 = q-row -> per-lane softmax scalars.
// O^T = V^T * P^T. Single-buffer LDS + register prefetch in EXPLICIT named
// registers (no arrays/lambdas: round-7's address-taken arrays went to
// scratch -> 107 MB of HBM writeback).
__global__ __launch_bounds__(256, 4) void attn_kernel(const __bf16* __restrict__ q,
                                                      const __bf16* __restrict__ kk,
                                                      const __bf16* __restrict__ vt,
                                                      __bf16* __restrict__ o) {
    int blk = blockIdx.x;
    int qt = 31 - (blk & 31);            // long blocks first
    int h = (blk >> 5) & 15;
    int b = blk >> 9;
    int rowbase = b * NSEQ;
    int t = threadIdx.x;
    int w = t >> 6, l = t & 63;
    int lrow = l & 15, lq = l >> 4;

    __shared__ __bf16 Kt[64 * 72];       // [key][d], stride 72
    __shared__ __bf16 Vs[64 * 72];       // [d][key], stride 72 (from vt)
    __shared__ __bf16 Ps[4 * 16 * 72];   // per-wave P^T strip as [qrow][key]
    __bf16* pw = &Ps[w * 16 * 72];

    const __bf16* kbase = kk + (size_t)rowbase * DIM + h * 64;
    const __bf16* vbase = vt + (size_t)(h * 64) * 4096 + b * 2048;

    // staging addresses: thread covers rows {row0, row0+32} at col c8
    int row0 = t >> 3;
    int c8 = (t & 7) * 8;

    // Q as B-fragment: B[n=qrow=l&15][k=d=(l>>4)*8+j] — direct from global
    const __bf16* qp = q + (size_t)(rowbase + qt * 64 + w * 16 + lrow) * DIM + h * 64;
    bf16x8 qb0 = *(const bf16x8*)(qp + lq * 8);
    bf16x8 qb1 = *(const bf16x8*)(qp + 32 + lq * 8);

    f32x4 oacc[4] = {};                  // O^T: [d-chunk][d-reg], col = qrow
    float m_r = -1e30f, l_r = 0.0f;      // per-lane scalars (qrow = lrow)

    // explicit prefetch registers (promotable: never address-taken)
    uint4 kr0, kr1, vr0, vr1;
    kr0 = *(const uint4*)(kbase + (size_t)row0 * DIM + c8);
    kr1 = *(const uint4*)(kbase + (size_t)(row0 + 32) * DIM + c8);
    vr0 = *(const uint4*)(vbase + (size_t)row0 * 4096 + c8);
    vr1 = *(const uint4*)(vbase + (size_t)(row0 + 32) * 4096 + c8);
    *(uint4*)&Kt[row0 * 72 + c8] = kr0;
    *(uint4*)&Kt[(row0 + 32) * 72 + c8] = kr1;
    *(uint4*)&Vs[row0 * 72 + c8] = vr0;
    *(uint4*)&Vs[(row0 + 32) * 72 + c8] = vr1;
    __syncthreads();

    for (int jt = 0; jt <= qt; ++jt) {
        if (jt < qt) {                   // register prefetch of next K/V tile
            int j0 = (jt + 1) * 64;
            kr0 = *(const uint4*)(kbase + (size_t)(j0 + row0) * DIM + c8);
            kr1 = *(const uint4*)(kbase + (size_t)(j0 + row0 + 32) * DIM + c8);
            vr0 = *(const uint4*)(vbase + (size_t)row0 * 4096 + j0 + c8);
            vr1 = *(const uint4*)(vbase + (size_t)(row0 + 32) * 4096 + j0 + c8);
        }

        // S^T strip (64 keys x 16 qrows): A = K[m=key][k=d], B = Q
        f32x4 st[4];
        #pragma unroll
        for (int ct = 0; ct < 4; ++ct) {
            f32x4 z = {};
            bf16x8 ka0 = *(const bf16x8*)&Kt[(ct * 16 + lrow) * 72 + lq * 8];
            bf16x8 ka1 = *(const bf16x8*)&Kt[(ct * 16 + lrow) * 72 + 32 + lq * 8];
            z = __builtin_amdgcn_mfma_f32_16x16x32_bf16(ka0, qb0, z, 0, 0, 0);
            z = __builtin_amdgcn_mfma_f32_16x16x32_bf16(ka1, qb1, z, 0, 0, 0);
            st[ct] = z;   // key = ct*16 + lq*4 + r, qrow(local) = lrow
        }
        // causal mask on diagonal tile: key_local > qrow_local
        if (jt == qt) {
            int qr = w * 16 + lrow;
            #pragma unroll
            for (int ct = 0; ct < 4; ++ct)
                #pragma unroll
                for (int r = 0; r < 4; ++r)
                    if (ct * 16 + lq * 4 + r > qr) st[ct][r] = -3.0e38f;
        }
        // per-lane online softmax (16 keys in-lane, 2 shuffles across lane groups)
        float mx = st[0][0];
        #pragma unroll
        for (int ct = 0; ct < 4; ++ct)
            #pragma unroll
            for (int r = 0; r < 4; ++r) mx = fmaxf(mx, st[ct][r]);
        mx = fmaxf(mx, __shfl_xor(mx, 16, 64));
        mx = fmaxf(mx, __shfl_xor(mx, 32, 64));
        float mnew = fmaxf(m_r, mx);
        float alpha = __expf(m_r - mnew);
        float ps = 0.0f;
        #pragma unroll
        for (int ct = 0; ct < 4; ++ct)
            #pragma unroll
            for (int r = 0; r < 4; ++r) {
                float p = __expf(st[ct][r] - mnew);
                st[ct][r] = p;
                ps += p;
            }
        ps += __shfl_xor(ps, 16, 64);
        ps += __shfl_xor(ps, 32, 64);
        l_r = l_r * alpha + ps;
        m_r = mnew;

        // P^T -> LDS as [qrow][key] row-major (per-wave strip, no barrier)
        #pragma unroll
        for (int ct = 0; ct < 4; ++ct)
            #pragma unroll
            for (int r = 0; r < 4; ++r)
                pw[lrow * 72 + ct * 16 + lq * 4 + r] = (__bf16)st[ct][r];
        // rescale O^T by per-lane alpha
        #pragma unroll
        for (int ct = 0; ct < 4; ++ct)
            #pragma unroll
            for (int r = 0; r < 4; ++r) oacc[ct][r] *= alpha;
        // O^T += V^T * P^T: A = V^T[m=d][k=key] from Vs, B = P^T[n=qrow][k=key]
        bf16x8 pb0 = *(const bf16x8*)&pw[lrow * 72 + lq * 8];
        bf16x8 pb1 = *(const bf16x8*)&pw[lrow * 72 + 32 + lq * 8];
        #pragma unroll
        for (int ct = 0; ct < 4; ++ct) {
            bf16x8 va0 = *(const bf16x8*)&Vs[(ct * 16 + lrow) * 72 + lq * 8];
            bf16x8 va1 = *(const bf16x8*)&Vs[(ct * 16 + lrow) * 72 + 32 + lq * 8];
            oacc[ct] = __builtin_amdgcn_mfma_f32_16x16x32_bf16(va0, pb0, oacc[ct], 0, 0, 0);
            oacc[ct] = __builtin_amdgcn_mfma_f32_16x16x32_bf16(va1, pb1, oacc[ct], 0, 0, 0);
        }
        __syncthreads();                 // all waves done reading Kt/Vs
        if (jt < qt) {                   // overwrite with prefetched tile
            *(uint4*)&Kt[row0 * 72 + c8] = kr0;
            *(uint4*)&Kt[(row0 + 32) * 72 + c8] = kr1;
            *(uint4*)&Vs[row0 * 72 + c8] = vr0;
            *(uint4*)&Vs[(row0 + 32) * 72 + c8] = vr1;
        }
        __syncthreads();
    }
    // epilogue: O^T C-layout -> o[qrow][d]; lane writes 4 consecutive d per chunk
    float rcp = 1.0f / l_r;
    const size_t orow = (size_t)(rowbase + qt * 64 + w * 16 + lrow) * DIM + h * 64;
    #pragma unroll
    for (int ct = 0; ct < 4; ++ct) {
        union { uint2 u; __bf16 h4[4]; } pk;
        #pragma unroll
        for (int r = 0; r < 4; ++r) pk.h4[r] = (__bf16)(oacc[ct][r] * rcp);
        *(uint2*)(o + orow + ct * 16 + lq * 4) = pk.u;
    }
}

extern "C" void kernel_launch(void* const* d_in, const int* in_sizes, int n_in,
                              void* d_out, int out_size, void* d_ws, size_t ws_size,
                              hipStream_t stream) {
    const float* tokens = (const float*)d_in[0];
    const float* gamma  = (const float*)d_in[1];
    const float* wq = (const float*)d_in[2];
    const float* wk = (const float*)d_in[3];
    const float* wv = (const float*)d_in[4];
    const float* wo = (const float*)d_in[5];

    __bf16* ws  = (__bf16*)d_ws;
    __bf16* x   = ws;                           // 4096*1024 (dead after V^T GEMM)
    __bf16* qb  = x   + (size_t)4096 * 1024;
    __bf16* kb  = qb  + (size_t)4096 * 1024;
    __bf16* vtb = kb  + (size_t)4096 * 1024;    // V^T: 1024 x 4096
    __bf16* ao  = x;                            // alias: attn out reuses x's buffer
    float*  out = (float*)d_out;

    rmsnorm_kernel<<<4096, 256, 0, stream>>>(tokens, gamma, x);

    dim3 gg(32, 8);
    gemm_bt_kernel<__bf16, float, __bf16><<<gg, 256, 0, stream>>>(x, wq, qb, 0.125f, 1024);
    gemm_bt_kernel<__bf16, float, __bf16><<<gg, 256, 0, stream>>>(x, wk, kb, 1.0f, 1024);
    // V^T directly: C'[j,i] = sum_k wv[j,k] x[i,k]  ->  vt (1024 x 4096)
    dim3 gv(8, 32);
    gemm_bt_kernel<float, __bf16, __bf16><<<gv, 256, 0, stream>>>(wv, x, vtb, 1.0f, 4096);

    rope_kernel<<<8192, 256, 0, stream>>>(qb);
    rope_kernel<<<8192, 256, 0, stream>>>(kb);

    attn_kernel<<<1024, 256, 0, stream>>>(qb, kb, vtb, ao);

    gemm_bt_kernel<__bf16, float, float><<<gg, 256, 0, stream>>>(ao, wo, out, 1.0f, 1024);
}